// Round 2
// baseline (425.310 us; speedup 1.0000x reference)
//
#include <hip/hip_runtime.h>
#include <hip/hip_cooperative_groups.h>
#include <hip/hip_bf16.h>
namespace cg = cooperative_groups;

#define NN 20000
#define EE 320000
#define E4 (EE/4)
#define KK 4
#define FIN 512
#define FHID 256
#define FOUT 128
#define FHD 256
#define NH (2*FOUT+3)   // 259
#define CAP1 1024
#define MS (CAP1+2)
#define CAP2 16384
#define T3 8
#define GRID 512
#define BLK 256

__device__ __forceinline__ float dinvf(int indeg) {
  // degree includes the self-loop -> always >= 1
  return rsqrtf((float)(indeg + 1));
}
__device__ __forceinline__ int aload(const int* p) {
  return __hip_atomic_load(p, __ATOMIC_RELAXED, __HIP_MEMORY_SCOPE_AGENT);
}

__global__ __launch_bounds__(BLK, 2) void mega(
    const float* __restrict__ x, const int* __restrict__ ei, const float* __restrict__ value,
    const int* __restrict__ idx, const float* __restrict__ W1, const float* __restrict__ b1,
    const float* __restrict__ W2, const float* __restrict__ b2, const float* __restrict__ Wd,
    const float* __restrict__ bd, const float* __restrict__ Wp, const float* __restrict__ bp,
    float* __restrict__ out, int* __restrict__ deg, int* __restrict__ cnt1,
    int* __restrict__ cnt2, int* __restrict__ L1src, int* __restrict__ L1sel,
    int* __restrict__ L2u, int* __restrict__ L2slot, float* __restrict__ L2norm,
    float* __restrict__ h1, float* __restrict__ HW2) {
  cg::grid_group grid = cg::this_grid();
  const int tid = threadIdx.x, bid = blockIdx.x;
  const int gsz = gridDim.x * BLK;
  const int gtid = bid * BLK + tid;

  __shared__ union {
    struct { int node[MS]; float dinv[MS]; } c;                                   // 8.2 KB
    struct { float xs[T3][FIN]; float part[4][T3][FHID]; float sn[T3]; int ss[T3]; } d; // 48.1 KB
    struct { float hrow[FHID]; float pr[FHID]; } e;                               // 2 KB
    struct { float h[NH + 1]; float o[FHD]; float red[4]; } f;                    // 2 KB
  } sm;

  // ---- Phase A: zero deg + cnt1 + cnt2 (contiguous block) ----
  for (int i = gtid; i < KK * NN + 2 * KK; i += gsz) deg[i] = 0;
  grid.sync();

  // ---- Phase B: degree histogram (int atomics, exact) + collect edges into targets ----
  for (int i = gtid; i < KK * E4; i += gsz) {
    int k = i / E4, e4 = i - k * E4;
    const int* srcp = ei + (size_t)k * 2 * EE;
    int4 d4 = ((const int4*)(srcp + EE))[e4];
    int t0 = idx[2 * k], t1 = idx[2 * k + 1];
    int* dk = deg + k * NN;
    atomicAdd(dk + d4.x, 1); atomicAdd(dk + d4.y, 1);
    atomicAdd(dk + d4.z, 1); atomicAdd(dk + d4.w, 1);
    int ds[4] = {d4.x, d4.y, d4.z, d4.w};
    #pragma unroll
    for (int c = 0; c < 4; c++) {
      if (ds[c] == t0) {
        int p = atomicAdd(&cnt1[k], 1);
        if (p < CAP1) { L1src[k * CAP1 + p] = srcp[e4 * 4 + c]; L1sel[k * CAP1 + p] = 0; }
      }
      if (ds[c] == t1) {
        int p = atomicAdd(&cnt1[k], 1);
        if (p < CAP1) { L1src[k * CAP1 + p] = srcp[e4 * 4 + c]; L1sel[k * CAP1 + p] = 1; }
      }
    }
  }
  grid.sync();

  // ---- Phase C: per k: lazy-zero h1 slots, build slot table, self-append, scan2 ----
  for (int k = 0; k < KK; k++) {
    int m = min(aload(&cnt1[k]), CAP1) + 2;
    for (int i = gtid; i < m * FHID; i += gsz) h1[(size_t)k * MS * FHID + i] = 0.f;
    for (int i = tid; i < m; i += BLK) {
      int node = (i == 0) ? idx[2 * k] : (i == 1) ? idx[2 * k + 1] : L1src[k * CAP1 + i - 2];
      sm.c.node[i] = node;
      sm.c.dinv[i] = dinvf(deg[k * NN + node]);
    }
    __syncthreads();
    if (bid == 0 && tid < m) {  // self-loop entries, norm = dinv^2
      int p = atomicAdd(&cnt2[k], 1);
      if (p < CAP2) {
        L2u[k * CAP2 + p] = sm.c.node[tid];
        L2slot[k * CAP2 + p] = tid;
        L2norm[k * CAP2 + p] = sm.c.dinv[tid] * sm.c.dinv[tid];
      }
    }
    const int* srcp = ei + (size_t)k * 2 * EE;
    for (int i = gtid; i < E4; i += gsz) {
      int4 d4 = ((const int4*)(srcp + EE))[i];
      int ds[4] = {d4.x, d4.y, d4.z, d4.w};
      float sdin[4] = {-1.f, -1.f, -1.f, -1.f};
      for (int s = 0; s < m; s++) {
        int snode = sm.c.node[s];
        float sdv = sm.c.dinv[s];
        #pragma unroll
        for (int c = 0; c < 4; c++) {
          if (ds[c] == snode) {
            int u = srcp[i * 4 + c];
            if (sdin[c] < 0.f) sdin[c] = dinvf(deg[k * NN + u]);
            int p = atomicAdd(&cnt2[k], 1);
            if (p < CAP2) {
              L2u[k * CAP2 + p] = u; L2slot[k * CAP2 + p] = s; L2norm[k * CAP2 + p] = sdin[c] * sdv;
            }
          }
        }
      }
    }
    __syncthreads();
  }
  grid.sync();

  // ---- Phase D: h1[slot] += norm * (x[u] @ W1), 8 entries per block-tile ----
  {
    int n2s[KK], toff[KK + 1]; toff[0] = 0;
    for (int k = 0; k < KK; k++) {
      n2s[k] = min(aload(&cnt2[k]), CAP2);
      toff[k + 1] = toff[k] + (n2s[k] + T3 - 1) / T3;
    }
    const int ks = tid >> 6;            // kk slice 0..3 (128 kk each)
    const int jq = (tid & 63) << 2;     // j quad base
    for (int w = bid; w < toff[KK]; w += gridDim.x) {
      int k = 0; while (w >= toff[k + 1]) k++;
      int base = (w - toff[k]) * T3;
      int tcnt = min(T3, n2s[k] - base);
      __syncthreads();
      if (tid < tcnt) {
        sm.d.ss[tid] = L2slot[k * CAP2 + base + tid];
        sm.d.sn[tid] = L2norm[k * CAP2 + base + tid];
      }
      { // stage 8 x-rows (2KB each) into LDS, float4-coalesced
        int t = tid >> 5, lane = tid & 31;
        if (t < tcnt) {
          int u = L2u[k * CAP2 + base + t];
          const float4* xr = (const float4*)(x + (size_t)u * FIN);
          float4* xw = (float4*)sm.d.xs[t];
          xw[lane] = xr[lane]; xw[lane + 32] = xr[lane + 32];
          xw[lane + 64] = xr[lane + 64]; xw[lane + 96] = xr[lane + 96];
        }
      }
      __syncthreads();
      float acc[T3][4];
      #pragma unroll
      for (int t = 0; t < T3; t++) { acc[t][0] = acc[t][1] = acc[t][2] = acc[t][3] = 0.f; }
      const float* wbase = W1 + (size_t)(ks * 128) * FHID + jq;
      for (int c = 0; c < 128; c += 4) {
        float xv[T3][4];
        #pragma unroll
        for (int t = 0; t < T3; t++) {
          float4 v = *(const float4*)&sm.d.xs[t][ks * 128 + c];  // wave-uniform broadcast
          xv[t][0] = v.x; xv[t][1] = v.y; xv[t][2] = v.z; xv[t][3] = v.w;
        }
        #pragma unroll
        for (int cc = 0; cc < 4; cc++) {
          float4 wv = *(const float4*)(wbase + (size_t)(c + cc) * FHID);
          #pragma unroll
          for (int t = 0; t < T3; t++) {
            acc[t][0] += xv[t][cc] * wv.x; acc[t][1] += xv[t][cc] * wv.y;
            acc[t][2] += xv[t][cc] * wv.z; acc[t][3] += xv[t][cc] * wv.w;
          }
        }
      }
      #pragma unroll
      for (int t = 0; t < T3; t++) {
        float4 pv = make_float4(acc[t][0], acc[t][1], acc[t][2], acc[t][3]);
        *(float4*)&sm.d.part[ks][t][jq] = pv;
      }
      __syncthreads();
      for (int i = tid; i < T3 * FHID; i += BLK) {
        int t = i >> 8, j = i & (FHID - 1);
        if (t < tcnt) {
          float sv = sm.d.part[0][t][j] + sm.d.part[1][t][j] +
                     sm.d.part[2][t][j] + sm.d.part[3][t][j];
          atomicAdd(&h1[((size_t)k * MS + sm.d.ss[t]) * FHID + j], sv * sm.d.sn[t]);
        }
      }
    }
  }
  grid.sync();

  // ---- Phase E: HW2[slot] = relu(h1[slot]+b1) @ W2 (kk split across 2 half-blocks) ----
  {
    int ms[KK], soff[KK + 1]; soff[0] = 0;
    for (int k = 0; k < KK; k++) {
      ms[k] = min(aload(&cnt1[k]), CAP1) + 2;
      soff[k + 1] = soff[k] + ms[k];
    }
    const int eks = tid >> 7, ej = tid & 127;
    for (int w = bid; w < soff[KK]; w += gridDim.x) {
      int k = 0; while (w >= soff[k + 1]) k++;
      int s = w - soff[k];
      __syncthreads();
      { float v = h1[((size_t)k * MS + s) * FHID + tid] + b1[tid];
        sm.e.hrow[tid] = v > 0.f ? v : 0.f; }
      __syncthreads();
      float a = 0.f;
      const float* w2p = W2 + (size_t)(eks * 128) * FOUT + ej;
      #pragma unroll 8
      for (int kk2 = 0; kk2 < 128; kk2++) a += sm.e.hrow[eks * 128 + kk2] * w2p[(size_t)kk2 * FOUT];
      sm.e.pr[tid] = a;
      __syncthreads();
      if (eks == 0) HW2[((size_t)k * MS + s) * FOUT + ej] = sm.e.pr[ej] + sm.e.pr[128 + ej];
    }
  }
  grid.sync();

  // ---- Phase F: mu rows + decoder MLP -> sigmoid -> out[k] ----
  if (bid < KK) {
    int k = bid;
    int n1 = min(aload(&cnt1[k]), CAP1);
    int tsel = tid >> 7, j = tid & 127;
    int t = idx[2 * k + tsel];
    float dit = dinvf(deg[k * NN + t]);
    float acc = b2[j] + dit * dit * HW2[((size_t)k * MS + tsel) * FOUT + j];
    for (int i = 0; i < n1; i++) {
      if (L1sel[k * CAP1 + i] == tsel) {
        int s = L1src[k * CAP1 + i];
        float dis = dinvf(deg[k * NN + s]);
        acc += dis * dit * HW2[((size_t)k * MS + 2 + i) * FOUT + j];
      }
    }
    sm.f.h[tsel * FOUT + j] = acc;
    if (tid < 3) sm.f.h[2 * FOUT + tid] = value[k * 3 + tid];
    __syncthreads();
    float a2 = bd[tid];
    for (int i = 0; i < NH; i++) a2 += sm.f.h[i] * Wd[(size_t)i * FHD + tid];
    sm.f.o[tid] = a2 > 0.f ? a2 : 0.f;
    __syncthreads();
    float r = sm.f.o[tid] * Wp[tid];
    for (int off2 = 32; off2 > 0; off2 >>= 1) r += __shfl_down(r, off2);
    if ((tid & 63) == 0) sm.f.red[tid >> 6] = r;
    __syncthreads();
    if (tid == 0) {
      float ssum = sm.f.red[0] + sm.f.red[1] + sm.f.red[2] + sm.f.red[3] + bp[0];
      out[k] = 1.f / (1.f + expf(-ssum));
    }
  }
}

extern "C" void kernel_launch(void* const* d_in, const int* in_sizes, int n_in,
                              void* d_out, int out_size, void* d_ws, size_t ws_size,
                              hipStream_t stream) {
  const float* x     = (const float*)d_in[0];
  const int*   ei    = (const int*)d_in[1];
  const float* value = (const float*)d_in[2];
  const int*   idx   = (const int*)d_in[3];
  const float* W1    = (const float*)d_in[4];
  const float* b1    = (const float*)d_in[5];
  const float* W2    = (const float*)d_in[6];
  const float* b2    = (const float*)d_in[7];
  const float* Wd    = (const float*)d_in[8];
  const float* bd    = (const float*)d_in[9];
  const float* Wp    = (const float*)d_in[10];
  const float* bp    = (const float*)d_in[11];
  float* out = (float*)d_out;

  char* ws = (char*)d_ws;
  size_t off = 0;
  auto alloc = [&](size_t bytes) -> void* {
    void* p = ws + off;
    off = (off + bytes + 255) & ~(size_t)255;
    return p;
  };
  int* deg = (int*)alloc((size_t)(KK * NN + 2 * KK) * sizeof(int));
  int* cnt1 = deg + KK * NN;
  int* cnt2 = cnt1 + KK;
  int* L1src = (int*)alloc((size_t)KK * CAP1 * sizeof(int));
  int* L1sel = (int*)alloc((size_t)KK * CAP1 * sizeof(int));
  int* L2u = (int*)alloc((size_t)KK * CAP2 * sizeof(int));
  int* L2slot = (int*)alloc((size_t)KK * CAP2 * sizeof(int));
  float* L2norm = (float*)alloc((size_t)KK * CAP2 * sizeof(float));
  float* h1 = (float*)alloc((size_t)KK * MS * FHID * sizeof(float));
  float* HW2 = (float*)alloc((size_t)KK * MS * FOUT * sizeof(float));
  (void)ws_size; (void)in_sizes; (void)n_in; (void)out_size;

  void* args[] = {&x, &ei, &value, &idx, &W1, &b1, &W2, &b2, &Wd, &bd, &Wp, &bp,
                  &out, &deg, &cnt1, &cnt2, &L1src, &L1sel, &L2u, &L2slot, &L2norm,
                  &h1, &HW2};
  hipLaunchCooperativeKernel((void*)mega, dim3(GRID), dim3(BLK), args, 0, stream);
}

// Round 3
// 91.622 us; speedup vs baseline: 4.6420x; 4.6420x over previous
//
#include <hip/hip_runtime.h>
#include <hip/hip_bf16.h>

#define NN 20000
#define EE 320000
#define E4 (EE/4)
#define KK 4
#define FIN 512
#define FHID 256
#define FOUT 128
#define FHD 256
#define NH (2*FOUT+3)   // 259
#define CAP1 1024       // max L1 edges (edges into the 2 targets); expected ~32
#define MS2 128         // max unique slot nodes; expected ~35
#define BCAP 256        // max in-edges per slot node; expected ~16

__device__ __forceinline__ float dinvf(int indeg) {
  // reference deg includes the self-loop -> always >= 1
  return rsqrtf((float)(indeg + 1));
}

// K1: scan dst planes; collect edges whose dst is a target (L1 list)
__global__ __launch_bounds__(256) void k1_scanL1(const int* __restrict__ ei,
                                                 const int* __restrict__ idx,
                                                 int* __restrict__ cnt1,
                                                 int* __restrict__ L1src,
                                                 int* __restrict__ L1sel) {
  int k = blockIdx.y;
  int e4 = blockIdx.x * blockDim.x + threadIdx.x;
  if (e4 >= E4) return;
  const int* srcp = ei + (size_t)k * 2 * EE;
  int4 d4 = ((const int4*)(srcp + EE))[e4];
  int t0 = idx[2 * k], t1 = idx[2 * k + 1];
  int ds[4] = {d4.x, d4.y, d4.z, d4.w};
  #pragma unroll
  for (int c = 0; c < 4; c++) {
    if (ds[c] == t0) {
      int p = atomicAdd(&cnt1[k], 1);
      if (p < CAP1) { L1src[k * CAP1 + p] = srcp[e4 * 4 + c]; L1sel[k * CAP1 + p] = 0; }
    }
    if (ds[c] == t1) {
      int p = atomicAdd(&cnt1[k], 1);
      if (p < CAP1) { L1src[k * CAP1 + p] = srcp[e4 * 4 + c]; L1sel[k * CAP1 + p] = 1; }
    }
  }
}

// K2: register unique slot nodes (targets + L1 srcs) into reg[], single thread per k
__global__ __launch_bounds__(64) void k2_slots(const int* __restrict__ idx,
                                               const int* __restrict__ cnt1,
                                               const int* __restrict__ L1src,
                                               int* __restrict__ reg,
                                               int* __restrict__ slotNode,
                                               int* __restrict__ mslots) {
  int k = blockIdx.x;
  if (threadIdx.x != 0) return;
  int* rk = reg + (size_t)k * NN;
  int n1 = min(cnt1[k], CAP1);
  int m = 0;
  for (int i = 0; i < n1 + 2; i++) {
    int node = (i == 0) ? idx[2 * k] : (i == 1) ? idx[2 * k + 1] : L1src[k * CAP1 + i - 2];
    if (rk[node] == 0 && m < MS2) { rk[node] = m + 1; slotNode[k * MS2 + m] = node; m++; }
  }
  mslots[k] = m;
}

// K3: scan; if dst is a slot node, append src to that slot's bucket; flag src as deg-needed
__global__ __launch_bounds__(256) void k3_scanL2(const int* __restrict__ ei,
                                                 int* __restrict__ reg,
                                                 int* __restrict__ bcnt,
                                                 int* __restrict__ bucket) {
  int k = blockIdx.y;
  int e4 = blockIdx.x * blockDim.x + threadIdx.x;
  if (e4 >= E4) return;
  const int* srcp = ei + (size_t)k * 2 * EE;
  int4 d4 = ((const int4*)(srcp + EE))[e4];
  int* rk = reg + (size_t)k * NN;
  int ds[4] = {d4.x, d4.y, d4.z, d4.w};
  #pragma unroll
  for (int c = 0; c < 4; c++) {
    int rv = rk[ds[c]];
    if (rv > 0) {
      int s = rv - 1;
      int u = srcp[e4 * 4 + c];
      int p = atomicAdd(&bcnt[k * MS2 + s], 1);
      if (p < BCAP) bucket[((size_t)k * MS2 + s) * BCAP + p] = u;
      if (rk[u] == 0) rk[u] = -1;  // benign race: both writers store -1
    }
  }
}

// K4: scan; count in-degree only for flagged/registered nodes (~150 nodes, ~11K atomics)
__global__ __launch_bounds__(256) void k4_deg(const int* __restrict__ ei,
                                              const int* __restrict__ reg,
                                              int* __restrict__ deg) {
  int k = blockIdx.y;
  int e4 = blockIdx.x * blockDim.x + threadIdx.x;
  if (e4 >= E4) return;
  const int* dstp = ei + (size_t)k * 2 * EE + EE;
  int4 d4 = ((const int4*)dstp)[e4];
  const int* rk = reg + (size_t)k * NN;
  int ds[4] = {d4.x, d4.y, d4.z, d4.w};
  #pragma unroll
  for (int c = 0; c < 4; c++) {
    if (rk[ds[c]] != 0) atomicAdd(&deg[k * NN + ds[c]], 1);
  }
}

// K5: per slot: agg = dinv(s)*(dinv(s)*x[s] + sum dinv(u)*x[u]); GEMV1+relu+GEMV2 -> HW2[s]
__global__ __launch_bounds__(256) void k5_slotmlp(const int* __restrict__ slotNode,
                                                  const int* __restrict__ mslots,
                                                  const int* __restrict__ bcnt,
                                                  const int* __restrict__ bucket,
                                                  const int* __restrict__ deg,
                                                  const float* __restrict__ x,
                                                  const float* __restrict__ W1,
                                                  const float* __restrict__ b1,
                                                  const float* __restrict__ W2,
                                                  float* __restrict__ HW2) {
  __shared__ float aggS[FIN];
  __shared__ float hrow[FHID];
  __shared__ float pr[FHID];
  int k = blockIdx.y, s = blockIdx.x;
  if (s >= mslots[k]) return;
  int tid = threadIdx.x;
  int node = slotNode[k * MS2 + s];
  float dn = dinvf(deg[k * NN + node]);
  int nb = min(bcnt[k * MS2 + s], BCAP);
  // register-accumulated gather over bucket entries
  float a0 = dn * x[(size_t)node * FIN + tid];
  float a1 = dn * x[(size_t)node * FIN + tid + 256];
  const int* bk = bucket + ((size_t)k * MS2 + s) * BCAP;
  for (int e = 0; e < nb; e++) {
    int u = bk[e];
    float du = dinvf(deg[k * NN + u]);
    a0 += du * x[(size_t)u * FIN + tid];
    a1 += du * x[(size_t)u * FIN + tid + 256];
  }
  aggS[tid] = dn * a0;
  aggS[tid + 256] = dn * a1;
  __syncthreads();
  // GEMV1: h = relu(agg @ W1 + b1)
  float acc = 0.f;
  const float* w1p = W1 + tid;
  #pragma unroll 8
  for (int kk = 0; kk < FIN; kk++) acc += aggS[kk] * w1p[(size_t)kk * FHID];
  { float v = acc + b1[tid]; hrow[tid] = v > 0.f ? v : 0.f; }
  __syncthreads();
  // GEMV2: HW2[s] = h @ W2, kk split across 2 half-blocks
  int half = tid >> 7, j = tid & 127;
  float a = 0.f;
  const float* w2p = W2 + (size_t)(half * 128) * FOUT + j;
  #pragma unroll 8
  for (int kk = 0; kk < 128; kk++) a += hrow[half * 128 + kk] * w2p[(size_t)kk * FOUT];
  pr[tid] = a;
  __syncthreads();
  if (half == 0) HW2[((size_t)k * MS2 + s) * FOUT + j] = pr[j] + pr[128 + j];
}

// K6: mu rows for t0,t1 (+b2) via HW2 + reg lookups, then decoder MLP -> sigmoid -> out[k]
__global__ __launch_bounds__(256) void k6_decode(const float* __restrict__ HW2,
                                                 const float* __restrict__ b2,
                                                 const int* __restrict__ cnt1,
                                                 const int* __restrict__ L1src,
                                                 const int* __restrict__ L1sel,
                                                 const int* __restrict__ idx,
                                                 const int* __restrict__ reg,
                                                 const int* __restrict__ deg,
                                                 const float* __restrict__ value,
                                                 const float* __restrict__ Wd,
                                                 const float* __restrict__ bd,
                                                 const float* __restrict__ Wp,
                                                 const float* __restrict__ bp,
                                                 float* __restrict__ out) {
  __shared__ float h[NH + 1];
  __shared__ float o[FHD];
  __shared__ float red[4];
  int k = blockIdx.x;
  int tid = threadIdx.x;
  const int* rk = reg + (size_t)k * NN;
  int n1 = min(cnt1[k], CAP1);
  int tsel = tid >> 7, j = tid & 127;
  int t = idx[2 * k + tsel];
  float dit = dinvf(deg[k * NN + t]);
  int tslot = rk[t] - 1;
  float acc = b2[j] + dit * dit * HW2[((size_t)k * MS2 + tslot) * FOUT + j];
  for (int i = 0; i < n1; i++) {
    if (L1sel[k * CAP1 + i] == tsel) {
      int s = L1src[k * CAP1 + i];
      float dis = dinvf(deg[k * NN + s]);
      int sslot = rk[s] - 1;
      acc += dis * dit * HW2[((size_t)k * MS2 + sslot) * FOUT + j];
    }
  }
  h[tsel * FOUT + j] = acc;
  if (tid < 3) h[2 * FOUT + tid] = value[k * 3 + tid];
  __syncthreads();
  float a2 = bd[tid];
  for (int i = 0; i < NH; i++) a2 += h[i] * Wd[(size_t)i * FHD + tid];
  o[tid] = a2 > 0.f ? a2 : 0.f;
  __syncthreads();
  float r = o[tid] * Wp[tid];
  for (int off2 = 32; off2 > 0; off2 >>= 1) r += __shfl_down(r, off2);
  if ((tid & 63) == 0) red[tid >> 6] = r;
  __syncthreads();
  if (tid == 0) {
    float ssum = red[0] + red[1] + red[2] + red[3] + bp[0];
    out[k] = 1.f / (1.f + expf(-ssum));
  }
}

extern "C" void kernel_launch(void* const* d_in, const int* in_sizes, int n_in,
                              void* d_out, int out_size, void* d_ws, size_t ws_size,
                              hipStream_t stream) {
  const float* x     = (const float*)d_in[0];
  const int*   ei    = (const int*)d_in[1];
  const float* value = (const float*)d_in[2];
  const int*   idx   = (const int*)d_in[3];
  const float* W1    = (const float*)d_in[4];
  const float* b1    = (const float*)d_in[5];
  const float* W2    = (const float*)d_in[6];
  const float* b2    = (const float*)d_in[7];
  const float* Wd    = (const float*)d_in[8];
  const float* bd    = (const float*)d_in[9];
  const float* Wp    = (const float*)d_in[10];
  const float* bp    = (const float*)d_in[11];
  float* out = (float*)d_out;

  char* ws = (char*)d_ws;
  size_t off = 0;
  auto alloc = [&](size_t bytes) -> void* {
    void* p = ws + off;
    off = (off + bytes + 255) & ~(size_t)255;
    return p;
  };
  // --- zeroed region (one memset): reg, deg, bcnt, cnt1, mslots ---
  int* reg   = (int*)alloc((size_t)(2 * KK * NN + KK * MS2 + 2 * KK) * sizeof(int));
  int* deg   = reg + KK * NN;
  int* bcnt  = deg + KK * NN;
  int* cnt1  = bcnt + KK * MS2;
  int* mslots = cnt1 + KK;
  size_t zbytes = (size_t)(2 * KK * NN + KK * MS2 + 2 * KK) * sizeof(int);
  // --- non-zeroed scratch ---
  int* L1src = (int*)alloc((size_t)KK * CAP1 * sizeof(int));
  int* L1sel = (int*)alloc((size_t)KK * CAP1 * sizeof(int));
  int* slotNode = (int*)alloc((size_t)KK * MS2 * sizeof(int));
  int* bucket = (int*)alloc((size_t)KK * MS2 * BCAP * sizeof(int));
  float* HW2 = (float*)alloc((size_t)KK * MS2 * FOUT * sizeof(float));
  (void)ws_size; (void)in_sizes; (void)n_in; (void)out_size;

  hipMemsetAsync(reg, 0, zbytes, stream);

  dim3 escan((E4 + 255) / 256, KK);
  k1_scanL1<<<escan, 256, 0, stream>>>(ei, idx, cnt1, L1src, L1sel);
  k2_slots<<<dim3(KK), 64, 0, stream>>>(idx, cnt1, L1src, reg, slotNode, mslots);
  k3_scanL2<<<escan, 256, 0, stream>>>(ei, reg, bcnt, bucket);
  k4_deg<<<escan, 256, 0, stream>>>(ei, reg, deg);
  k5_slotmlp<<<dim3(MS2, KK), 256, 0, stream>>>(slotNode, mslots, bcnt, bucket, deg,
                                                x, W1, b1, W2, HW2);
  k6_decode<<<dim3(KK), 256, 0, stream>>>(HW2, b2, cnt1, L1src, L1sel, idx, reg, deg,
                                          value, Wd, bd, Wp, bp, out);
}